// Round 7
// baseline (313.781 us; speedup 1.0000x reference)
//
#include <hip/hip_runtime.h>
#include <hip/hip_bf16.h>

typedef short short8 __attribute__((ext_vector_type(8)));
typedef float f32x4 __attribute__((ext_vector_type(4)));

#define XS 136  // Xl row stride in bf16 elems: 128 + 8 pad

static __device__ inline short f2bf(float f) {
    unsigned u = __float_as_uint(f);
    unsigned r = (u + 0x7fffu + ((u >> 16) & 1u)) >> 16;
    return (short)r;
}
static __device__ inline float bf2f(short s) {
    return __uint_as_float(((unsigned)(unsigned short)s) << 16);
}

// prep: build two 128x256 bf16 fragment arrays in MFMA B-layout (16x16x32):
//   Wbc[k][n] = W1b[k][n] + W1c[k][n]   (item coefficient)
//   Wd [k][n] = W1d[k][n]               (dot coefficient; folded per-batch in din_main)
// frag[((t*4+s)*64+l)*8+j] = src[s*32 + (l>>4)*8 + j][t*16 + (l&15)]
// Also zero-inits the dynamic work-queue counter (re-done every launch).
__global__ void prep(const float* __restrict__ W1, short* __restrict__ Wbc,
                     short* __restrict__ Wd, int* __restrict__ counter) {
    int idx = blockIdx.x * 256 + threadIdx.x;    // 256 blocks -> 65536 threads
    if (idx == 0) *counter = 0;
    int half = idx >> 15;
    int i = idx & 32767;
    int j = i & 7;
    int l = (i >> 3) & 63;
    int s = (i >> 9) & 3;
    int t = i >> 11;
    int k = s * 32 + ((l >> 4) << 3) + j;
    int n = t * 16 + (l & 15);
    if (half == 0) Wbc[i] = f2bf(W1[(128 + k) * 256 + n] + W1[(256 + k) * 256 + n]);
    else           Wd[i]  = f2bf(W1[(384 + k) * 256 + n]);
}

// U[b][j] = b1[j] + sum_d target[b][d] * (W1a[d][j] - W1c[d][j]);  8 b-rows/block
__global__ void compute_u(const float* __restrict__ target, const float* __restrict__ W1,
                          const float* __restrict__ b1, float* __restrict__ U) {
    const int b8 = blockIdx.x;        // 256 blocks
    const int tid = threadIdx.x;      // j
    __shared__ float tl[1024];        // 8 rows x 128
#pragma unroll
    for (int k = 0; k < 4; k++) tl[k * 256 + tid] = target[b8 * 1024 + k * 256 + tid];
    __syncthreads();
    float acc[8] = {0.f, 0.f, 0.f, 0.f, 0.f, 0.f, 0.f, 0.f};
#pragma unroll 8
    for (int d = 0; d < 128; ++d) {
        float wud = W1[d * 256 + tid] - W1[(256 + d) * 256 + tid];
#pragma unroll
        for (int r = 0; r < 8; r++) acc[r] += tl[r * 128 + d] * wud;
    }
    float bj = b1[tid];
#pragma unroll
    for (int r = 0; r < 8; r++) U[(b8 * 8 + r) * 256 + tid] = acc[r] + bj;
}

// Persistent-block fused kernel: 1024 blocks x 4 waves; each block pulls batch
// indices from a device-scope atomic queue until empty (fixes the R4/R6
// static-imbalance tail: OccupancyPercent 17.6% with data-dependent nt=1..13).
// Per batch b:
//   Weff_b[k][j] = Wbc[k][j] + tgt[k]*Wd[k][j]   (registers, bf16)
//   h_pre[l][j]  = U[j] + item[l] @ Weff_b       (K=128 bf16 MFMA)
//   score[l]     = relu(h_pre[l]) @ W2 + b2
//   out[b][d]    = sum_{l<slen} score[l]*item[l][d]   (direct write)
// NOTE (R3 lesson): don't force min-waves 4 — VGPR cap would spill bfrag.
__launch_bounds__(256, 2)
__global__ void din_main(const float* __restrict__ target, const float* __restrict__ item_seq,
                         const int* __restrict__ seq_len, const float* __restrict__ W2,
                         const float* __restrict__ b2p, const short* __restrict__ Wbc,
                         const short* __restrict__ Wd, const float* __restrict__ U,
                         int* __restrict__ counter, float* __restrict__ out) {
    const int tid = threadIdx.x;
    const int lane = tid & 63;
    const int w = tid >> 6;      // wave 0..3
    const int col = lane & 15;   // MFMA C col / B-frag n
    const int q = lane >> 4;     // quad
    const int r = tid >> 4;      // staging row 0..15
    const int c = (tid & 15) << 3;
    const int d = tid & 127;
    const int g = tid >> 7;      // 0/1: m-half for out accumulation

    __shared__ __attribute__((aligned(16))) short Xl[2][16 * XS];
    __shared__ __attribute__((aligned(16))) float tsh[128];
    __shared__ __attribute__((aligned(16))) float scoreP[16][4];
    __shared__ float out_s[128];
    __shared__ int cur_b;

    // Batch-invariant constants (hoisted out of the persistent loop)
    const float b2 = b2p[0];
    float w2c[4];
#pragma unroll
    for (int i = 0; i < 4; i++) w2c[i] = W2[(w * 4 + i) * 16 + col];

    for (;;) {
        if (tid == 0) cur_b = atomicAdd(counter, 1);
        __syncthreads();
        const int b = cur_b;
        if (b >= 2048) return;

        const int slen = seq_len[b];
        const int nt = (slen + 15) >> 4;

        // Issue memory early: tile-0 prefetch + U + target (overlap bfrag build)
        float4 v0, v1;
        {
            const float4* src = (const float4*)(item_seq + (((size_t)b * 200 + r) * 128 + c));
            v0 = src[0]; v1 = src[1];
        }
        float u_c[4];
#pragma unroll
        for (int i = 0; i < 4; i++) u_c[i] = U[b * 256 + (w * 4 + i) * 16 + col];
        if (tid < 128) tsh[tid] = target[b * 128 + tid];
        __syncthreads();

        // Per-batch Weff B-fragments in registers: 4 n-tiles x 4 K-steps
        short8 bfrag[4][4];
#pragma unroll
        for (int s = 0; s < 4; s++) {
            const float4* tp = (const float4*)(tsh + s * 32 + q * 8);
            float4 ta = tp[0], tb = tp[1];
            float tk[8] = {ta.x, ta.y, ta.z, ta.w, tb.x, tb.y, tb.z, tb.w};
#pragma unroll
            for (int i = 0; i < 4; i++) {
                size_t off = ((size_t)((w * 4 + i) * 4 + s) * 64 + lane) * 8;
                short8 bc = *(const short8*)(Wbc + off);
                short8 dd = *(const short8*)(Wd + off);
                short8 e;
#pragma unroll
                for (int j = 0; j < 8; j++) e[j] = f2bf(bf2f(bc[j]) + tk[j] * bf2f(dd[j]));
                bfrag[i][s] = e;
            }
        }

        float out_val = 0.f;
        f32x4 acc[4];

        for (int mt = 0; mt < nt; ++mt) {
            const int l0 = mt * 16;
            short* xb = Xl[mt & 1];

            // Pack prefetched item rows -> bf16 LDS
            {
                float v[8] = {v0.x, v0.y, v0.z, v0.w, v1.x, v1.y, v1.z, v1.w};
                short8 p;
#pragma unroll
                for (int j = 0; j < 8; j++) p[j] = f2bf(v[j]);
                *(short8*)(xb + r * XS + c) = p;
            }
            __syncthreads();   // sync#1: Xl[cur] visible

            // Prefetch next tile (overlaps MFMA + epilogue)
            if (mt + 1 < nt) {
                int lr = l0 + 16 + r;
                if (lr > 199) lr = 199;   // clamp: masked later, stays in-bounds
                const float4* src = (const float4*)(item_seq + (((size_t)b * 200 + lr) * 128 + c));
                v0 = src[0]; v1 = src[1];
            }

#pragma unroll
            for (int i = 0; i < 4; i++) acc[i] = (f32x4){0.f, 0.f, 0.f, 0.f};
            const short* arow = xb + col * XS + q * 8;
#pragma unroll
            for (int s = 0; s < 4; s++) {
                short8 af = *(const short8*)(arow + s * 32);
#pragma unroll
                for (int i = 0; i < 4; i++)
                    acc[i] = __builtin_amdgcn_mfma_f32_16x16x32_bf16(af, bfrag[i][s], acc[i], 0, 0, 0);
            }

            // Epilogue: relu + W2 partial over this wave's 64 n-cols; 16-lane reduce
            float sv[4];
#pragma unroll
            for (int rg = 0; rg < 4; rg++) {
                float s0 = 0.f;
#pragma unroll
                for (int i = 0; i < 4; i++) {
                    float h = acc[i][rg] + u_c[i];
                    h = h > 0.f ? h : 0.f;
                    s0 += h * w2c[i];
                }
                sv[rg] = s0;
            }
#pragma unroll
            for (int off = 1; off < 16; off <<= 1) {
#pragma unroll
                for (int rg = 0; rg < 4; rg++) sv[rg] += __shfl_xor(sv[rg], off, 64);
            }
            if (col == 0) {
#pragma unroll
                for (int rg = 0; rg < 4; rg++) scoreP[q * 4 + rg][w] = sv[rg];
            }
            __syncthreads();   // sync#2: scoreP visible; Xl[cur] MFMA reads done

            // out_val += score[m] * item[l0+m][d]; 8 m's per thread half
#pragma unroll
            for (int mm = 0; mm < 8; mm++) {
                int m = g * 8 + mm;
                int l = l0 + m;
                float4 sp = *(const float4*)&scoreP[m][0];
                float s = (sp.x + sp.y) + (sp.z + sp.w) + b2;
                s = (l < slen) ? s : 0.f;
                out_val += s * bf2f(xb[m * XS + d]);
            }
        }

        __syncthreads();
        if (g == 1) out_s[d] = out_val;
        __syncthreads();
        if (g == 0) out[b * 128 + d] = out_val + out_s[d];
        // loop: next batch's writes to tsh/Xl/scoreP/out_s are all barrier-guarded
    }
}

extern "C" void kernel_launch(void* const* d_in, const int* in_sizes, int n_in,
                              void* d_out, int out_size, void* d_ws, size_t ws_size,
                              hipStream_t stream) {
    const float* target   = (const float*)d_in[0];
    const float* item_seq = (const float*)d_in[1];
    const int*   seq_len  = (const int*)d_in[2];
    const float* W1       = (const float*)d_in[3];
    const float* b1       = (const float*)d_in[4];
    const float* W2       = (const float*)d_in[5];
    const float* b2       = (const float*)d_in[6];
    float* out = (float*)d_out;

    char* ws = (char*)d_ws;
    short* Wbc   = (short*)ws;                   // 32768*2 = 65536 B
    short* Wd    = (short*)(ws + 65536);         // 65536 B
    float* U     = (float*)(ws + 131072);        // 2048*256*4 = 2 MB
    int* counter = (int*)(ws + 131072 + 2097152);

    prep<<<256, 256, 0, stream>>>(W1, Wbc, Wd, counter);
    compute_u<<<256, 256, 0, stream>>>(target, W1, b1, U);
    din_main<<<1024, 256, 0, stream>>>(target, item_seq, seq_len, W2, b2, Wbc, Wd, U, counter, out);
}